// Round 7
// baseline (107.586 us; speedup 1.0000x reference)
//
#include <hip/hip_runtime.h>

typedef __attribute__((ext_vector_type(4))) float float4v;
typedef __attribute__((ext_vector_type(8))) short short8;
typedef __attribute__((ext_vector_type(16))) float f32x16;

#define C_IN 32
#define C_OUT 32
#define HH 224
#define WW 224
#define HW (HH * WW)
#define STRIPE 14                 // output rows per block; 224 = 16 stripes x 32 imgs = 512 blocks
#define RING_PX 226               // w = -1 .. 224 (halo columns at px 0 and 225)
#define PIX_STRIDE 80             // 64B data (32ch bf16) + 16B pad; conflict-free b128
#define ROW_BYTES (RING_PX * PIX_STRIDE)  // 18,080
#define NTHR 512

// fp32 -> bf16 bits, round-to-nearest-even
__device__ __forceinline__ short f2bf(float f) {
    unsigned u = __float_as_uint(f);
    u += 0x7FFFu + ((u >> 16) & 1u);
    return (short)(u >> 16);
}
// pack two bf16 (even ch in low half) into one dword
__device__ __forceinline__ unsigned pack2(float e, float o) {
    return (unsigned)(unsigned short)f2bf(e) | ((unsigned)(unsigned short)f2bf(o) << 16);
}

// Rolling row-window conv, 2 blocks/CU: block = (image, 14-row stripe), full width.
// R6 lesson: with 1 block/CU every row-step pays a dead vmcnt(0)+barrier drain
// (~1-2k cy) with nothing to fill it; a co-resident block overlaps it.
// LDS 54.2KB x 2 blocks = 108.5KB/CU; VGPR 116 -> 4 waves/SIMD.
__global__ __launch_bounds__(NTHR) __attribute__((amdgpu_waves_per_eu(2, 2)))
void conv3x3_rows(const float* __restrict__ X, const float* __restrict__ Wt,
                  const float* __restrict__ Bias, float* __restrict__ Y) {
    __shared__ __align__(16) char ring0[ROW_BYTES];
    __shared__ __align__(16) char ring1[ROW_BYTES];
    __shared__ __align__(16) char ring2[ROW_BYTES];   // 54,240 B total

    const int tid = threadIdx.x;
    const int lane = tid & 63;
    const int wid = tid >> 6;      // wave 0..7
    const int col = lane & 31;     // A: out-channel; B/C: pixel col
    const int khalf = lane >> 5;   // K-half of MFMA K=16 slice

    // --- W fragments (A operand: M=32 k_out, K=16 c-slice) ---
    short8 wfrag[18];
#pragma unroll
    for (int rs = 0; rs < 9; ++rs) {
#pragma unroll
        for (int ch = 0; ch < 2; ++ch) {
            short8 f;
#pragma unroll
            for (int j = 0; j < 8; ++j) {
                int c = ch * 16 + khalf * 8 + j;
                f[j] = f2bf(Wt[(col * C_IN + c) * 9 + rs]);  // W[k_out][c][r][s]
            }
            wfrag[rs * 2 + ch] = f;
        }
    }

    // --- Bias in C-fragment order: row(k_out) = (i&3) + 8*(i>>2) + 4*khalf ---
    f32x16 biasv;
#pragma unroll
    for (int i = 0; i < 16; ++i)
        biasv[i] = Bias[(i & 3) + 8 * (i >> 2) + 4 * khalf];

    // --- Staging geometry: unit u = w4*16 + cp (cp = channel-pair, w4 = 4px group) ---
    const int cp0 = tid & 15, w40 = tid >> 4;         // unit0 = tid (896 units total)
    const int t1 = tid + NTHR;
    const bool has1 = (tid < 896 - NTHR);             // threads 0..383 take a second unit
    const int cp1 = t1 & 15, w41 = t1 >> 4;
    const int ge0 = (2 * cp0) * HW + 4 * w40;         // float offsets from (n, hh) row base
    const int go0 = ge0 + HW;
    const int ge1 = (2 * cp1) * HW + 4 * w41;
    const int go1 = ge1 + HW;

    const int bid = blockIdx.x;
    const int n = bid >> 4;                // image
    const int h1 = (bid & 15) * STRIPE;    // stripe start row
    const float* Xn = X + n * C_IN * HW;

    float4v e0, o0, e1, o1;
    const short8 z8 = {0, 0, 0, 0, 0, 0, 0, 0};

#define LOAD_ROW(hh) do {                                          \
        const float* rp = Xn + (hh) * WW;                          \
        e0 = *(const float4v*)(rp + ge0);                          \
        o0 = *(const float4v*)(rp + go0);                          \
        if (has1) {                                                \
            e1 = *(const float4v*)(rp + ge1);                      \
            o1 = *(const float4v*)(rp + go1);                      \
        }                                                          \
    } while (0)

#define WRITE_ROW(sb) do {                                         \
        char* wb0 = (sb) + (1 + 4 * w40) * PIX_STRIDE + cp0 * 4;   \
        *(unsigned*)(wb0                  ) = pack2(e0[0], o0[0]); \
        *(unsigned*)(wb0 +     PIX_STRIDE ) = pack2(e0[1], o0[1]); \
        *(unsigned*)(wb0 + 2 * PIX_STRIDE ) = pack2(e0[2], o0[2]); \
        *(unsigned*)(wb0 + 3 * PIX_STRIDE ) = pack2(e0[3], o0[3]); \
        if (has1) {                                                \
            char* wb1 = (sb) + (1 + 4 * w41) * PIX_STRIDE + cp1 * 4; \
            *(unsigned*)(wb1                  ) = pack2(e1[0], o1[0]); \
            *(unsigned*)(wb1 +     PIX_STRIDE ) = pack2(e1[1], o1[1]); \
            *(unsigned*)(wb1 + 2 * PIX_STRIDE ) = pack2(e1[2], o1[2]); \
            *(unsigned*)(wb1 + 3 * PIX_STRIDE ) = pack2(e1[3], o1[3]); \
        }                                                          \
        if (tid < 8) {  /* zero the two w-halo pixels (px 0 and 225) */ \
            int px = (tid < 4) ? 0 : (RING_PX - 1);                \
            *(short8*)((sb) + px * PIX_STRIDE + (tid & 3) * 16) = z8; \
        }                                                          \
    } while (0)

#define ZERO_ROW(sb) do {                                          \
        for (int i = tid; i < ROW_BYTES / 16; i += NTHR)           \
            *(short8*)((sb) + i * 16) = z8;                        \
    } while (0)

    // ===== Prologue: fill ring with rows h1-1, h1, h1+1 =====
#pragma unroll
    for (int j = 0; j < 3; ++j) {
        int hh = h1 - 1 + j;
        char* sb = (j == 0) ? ring0 : (j == 1) ? ring1 : ring2;
        if (hh >= 0 && hh < HH) {   // block-uniform
            LOAD_ROW(hh);
            WRITE_ROW(sb);
        } else {
            ZERO_ROW(sb);
        }
    }
    __syncthreads();

    // ===== Main loop: rA = row h-1, rB = h, rC = h+1; write h+2 over rA =====
    char *rA = ring0, *rB = ring1, *rC = ring2;
    const int pcol = col * PIX_STRIDE + khalf * 16;

    for (int h = h1; h < h1 + STRIPE; ++h) {
        const int hh = h + 2;
        const bool do_pref = (hh <= h1 + STRIPE);   // last needed row = h1+STRIPE
        const bool validrow = do_pref && (hh < HH); // block-uniform

        // Phase 1: issue next row's global loads (waits land in Phase 4, after MFMA)
        if (validrow) LOAD_ROW(hh);

        // Phase 2: compute output row h; wave w owns px [32w, 32w+32)
        if (wid < 7) {
            const int px0 = wid * 32;
            f32x16 acc = biasv;   // bias folded into accumulator init
            const int pb = px0 * PIX_STRIDE + pcol;
#pragma unroll
            for (int rs = 0; rs < 9; ++rs) {
                const int r = rs / 3, s = rs - 3 * r;
                const char* rb = (r == 0) ? rA : (r == 1) ? rB : rC;
                const int addr = pb + s * PIX_STRIDE;
#pragma unroll
                for (int ch = 0; ch < 2; ++ch) {
                    short8 bfrag = *(const short8*)(rb + addr + ch * 32);
                    acc = __builtin_amdgcn_mfma_f32_32x32x16_bf16(
                        wfrag[rs * 2 + ch], bfrag, acc, 0, 0, 0);
                }
            }
            const int ybase = n * C_OUT * HW + h * WW + px0 + col;
#pragma unroll
            for (int i = 0; i < 16; ++i) {
                int ko = (i & 3) + 8 * (i >> 2) + 4 * khalf;
                Y[ybase + ko * HW] = acc[i];
            }
        }

        // Phase 3: all reads of rA done before it is overwritten
        __syncthreads();

        // Phase 4: convert + write row h+2 into the expired slot
        if (validrow) {
            WRITE_ROW(rA);
        } else if (do_pref) {
            ZERO_ROW(rA);   // image bottom edge
        }
        __syncthreads();

        // rotate ring
        char* t = rA; rA = rB; rB = rC; rC = t;
    }
#undef LOAD_ROW
#undef WRITE_ROW
#undef ZERO_ROW
}

extern "C" void kernel_launch(void* const* d_in, const int* in_sizes, int n_in,
                              void* d_out, int out_size, void* d_ws, size_t ws_size,
                              hipStream_t stream) {
    const float* X = (const float*)d_in[0];
    const float* W = (const float*)d_in[1];
    const float* B = (const float*)d_in[2];
    float* Y = (float*)d_out;
    // 512 blocks = 32 images x 16 stripes; 2 resident per CU (LDS 108.5KB/CU)
    conv3x3_rows<<<dim3(512), dim3(NTHR), 0, stream>>>(X, W, B, Y);
}

// Round 8
// 105.262 us; speedup vs baseline: 1.0221x; 1.0221x over previous
//
#include <hip/hip_runtime.h>

typedef __attribute__((ext_vector_type(4))) float float4v;
typedef __attribute__((ext_vector_type(8))) short short8;
typedef __attribute__((ext_vector_type(16))) float f32x16;

#define C_IN 32
#define C_OUT 32
#define HH 224
#define WW 224
#define HW (HH * WW)
#define STRIPE 28                 // output rows per block; 8 stripes x 32 imgs = 256 blocks
#define RING_PX 226               // w = -1 .. 224 (halo columns at px 0 and 225)
#define PIX_STRIDE 80             // 64B data (32ch bf16) + 16B pad; conflict-free b128
#define ROW_BYTES (RING_PX * PIX_STRIDE)  // 18,080
#define NRING 6                   // 6-row ring -> write slots disjoint from read slots
#define NTHR 512

// fp32 -> bf16 bits, round-to-nearest-even
__device__ __forceinline__ short f2bf(float f) {
    unsigned u = __float_as_uint(f);
    u += 0x7FFFu + ((u >> 16) & 1u);
    return (short)(u >> 16);
}
__device__ __forceinline__ unsigned pack2(float e, float o) {
    return (unsigned)(unsigned short)f2bf(e) | ((unsigned)(unsigned short)f2bf(o) << 16);
}

// Rolling 2-row-step conv. R6/R7 lesson: ~60% of each row-step was
// vmcnt(0)+barrier drain (2 barriers/row) and ds latency; occupancy changes
// (R3,R7) are no-ops. This version: ring-of-6 -> ONE barrier per 2-row step
// (read slots h-1..h+2 disjoint from write slots h+3,h+4; prior readers fenced
// by the previous barrier), 4-row fragment reuse (24 ds_read / 36 MFMA), and
// 2-row prefetch. 1 block/CU (LDS 108.5KB).
__global__ __launch_bounds__(NTHR) __attribute__((amdgpu_waves_per_eu(2, 2)))
void conv3x3_rows2(const float* __restrict__ X, const float* __restrict__ Wt,
                   const float* __restrict__ Bias, float* __restrict__ Y) {
    __shared__ __align__(16) char ring[NRING * ROW_BYTES];  // 108,480 B

    const int tid = threadIdx.x;
    const int lane = tid & 63;
    const int wid = tid >> 6;      // wave 0..7
    const int col = lane & 31;     // A: out-channel; B/C: pixel col
    const int khalf = lane >> 5;   // K-half of MFMA K=16 slice

    // --- W fragments (A operand: M=32 k_out, K=16 c-slice) ---
    short8 wfrag[18];
#pragma unroll
    for (int rs = 0; rs < 9; ++rs) {
#pragma unroll
        for (int ch = 0; ch < 2; ++ch) {
            short8 f;
#pragma unroll
            for (int j = 0; j < 8; ++j) {
                int c = ch * 16 + khalf * 8 + j;
                f[j] = f2bf(Wt[(col * C_IN + c) * 9 + rs]);  // W[k_out][c][r][s]
            }
            wfrag[rs * 2 + ch] = f;
        }
    }

    // --- Bias in C-fragment order: row(k_out) = (i&3) + 8*(i>>2) + 4*khalf ---
    f32x16 biasv;
#pragma unroll
    for (int i = 0; i < 16; ++i)
        biasv[i] = Bias[(i & 3) + 8 * (i >> 2) + 4 * khalf];

    // --- Staging geometry: unit u = w4*16 + cp (cp = channel-pair, w4 = 4px group) ---
    const int cp0 = tid & 15, w40 = tid >> 4;         // unit0 = tid (896 units)
    const int t1 = tid + NTHR;
    const bool has1 = (tid < 896 - NTHR);             // threads 0..383 take 2nd unit
    const int cp1 = t1 & 15, w41 = t1 >> 4;
    const int ge0 = (2 * cp0) * HW + 4 * w40;
    const int go0 = ge0 + HW;
    const int ge1 = (2 * cp1) * HW + 4 * w41;
    const int go1 = ge1 + HW;

    const int bid = blockIdx.x;
    const int n = bid >> 3;
    const int h1 = (bid & 7) * STRIPE;
    const float* Xn = X + n * C_IN * HW;

    float4v ea0, oa0, ea1, oa1;   // staged row h+3
    float4v eb0, ob0, eb1, ob1;   // staged row h+4
    const short8 z8 = {0, 0, 0, 0, 0, 0, 0, 0};

#define LOAD_ROW(hh, E0, O0, E1, O1) do {                          \
        const float* rp = Xn + (hh) * WW;                          \
        E0 = *(const float4v*)(rp + ge0);                          \
        O0 = *(const float4v*)(rp + go0);                          \
        if (has1) {                                                \
            E1 = *(const float4v*)(rp + ge1);                      \
            O1 = *(const float4v*)(rp + go1);                      \
        }                                                          \
    } while (0)

#define WRITE_ROW(sb, E0, O0, E1, O1) do {                         \
        char* wb0 = (sb) + (1 + 4 * w40) * PIX_STRIDE + cp0 * 4;   \
        *(unsigned*)(wb0                  ) = pack2(E0[0], O0[0]); \
        *(unsigned*)(wb0 +     PIX_STRIDE ) = pack2(E0[1], O0[1]); \
        *(unsigned*)(wb0 + 2 * PIX_STRIDE ) = pack2(E0[2], O0[2]); \
        *(unsigned*)(wb0 + 3 * PIX_STRIDE ) = pack2(E0[3], O0[3]); \
        if (has1) {                                                \
            char* wb1 = (sb) + (1 + 4 * w41) * PIX_STRIDE + cp1 * 4; \
            *(unsigned*)(wb1                  ) = pack2(E1[0], O1[0]); \
            *(unsigned*)(wb1 +     PIX_STRIDE ) = pack2(E1[1], O1[1]); \
            *(unsigned*)(wb1 + 2 * PIX_STRIDE ) = pack2(E1[2], O1[2]); \
            *(unsigned*)(wb1 + 3 * PIX_STRIDE ) = pack2(E1[3], O1[3]); \
        }                                                          \
        if (tid < 8) {  /* zero w-halo pixels (px 0, 225) */       \
            int px = (tid < 4) ? 0 : (RING_PX - 1);                \
            *(short8*)((sb) + px * PIX_STRIDE + (tid & 3) * 16) = z8; \
        }                                                          \
    } while (0)

#define ZERO_ROW(sb) do {                                          \
        for (int i = tid; i < ROW_BYTES / 16; i += NTHR)           \
            *(short8*)((sb) + i * 16) = z8;                        \
    } while (0)

    // ===== Prologue: fill rows h1-1 .. h1+2 into slots (row+6)%6 =====
#pragma unroll
    for (int j = 0; j < 4; ++j) {
        int hh = h1 - 1 + j;
        char* sb = ring + ((hh + NRING) % NRING) * ROW_BYTES;
        if (hh >= 0) {  // block-uniform; hh < HH always here (h1+2 <= 198)
            LOAD_ROW(hh, ea0, oa0, ea1, oa1);
            WRITE_ROW(sb, ea0, oa0, ea1, oa1);
        } else {
            ZERO_ROW(sb);
        }
    }
    __syncthreads();

    // ===== Main loop: compute rows (h, h+1); prefetch rows (h+3, h+4) =====
    int s0 = (h1 + 5) % NRING;            // slot of row h-1
    const int pcol = col * PIX_STRIDE + khalf * 16;

    for (int h = h1; h < h1 + STRIPE; h += 2) {
        const int ha = h + 3, hb = h + 4;
        const bool dp = (hb <= h1 + STRIPE);       // prefetch needed (uniform)
        const bool va = dp && (ha < HH);
        const bool vb = dp && (hb < HH);

        // P1: issue prefetch loads (waits land at first use in P4, after MFMA)
        if (va) LOAD_ROW(ha, ea0, oa0, ea1, oa1);
        if (vb) LOAD_ROW(hb, eb0, ob0, eb1, ob1);

        // P2: compute rows h, h+1. 4-row window, middle rows' frags reused.
        const char* r0p = ring + s0 * ROW_BYTES;                    // row h-1
        const char* r1p = ring + ((s0 + 1) % NRING) * ROW_BYTES;    // row h
        const char* r2p = ring + ((s0 + 2) % NRING) * ROW_BYTES;    // row h+1
        const char* r3p = ring + ((s0 + 3) % NRING) * ROW_BYTES;    // row h+2
        f32x16 acc0, acc1;
        if (wid < 7) {
            const int px0 = wid * 32;
            acc0 = biasv;
            acc1 = biasv;
            const int pb = px0 * PIX_STRIDE + pcol;
#pragma unroll
            for (int s = 0; s < 3; ++s) {
#pragma unroll
                for (int ch = 0; ch < 2; ++ch) {
                    const int addr = pb + s * PIX_STRIDE + ch * 32;
                    short8 f0 = *(const short8*)(r0p + addr);
                    short8 f1 = *(const short8*)(r1p + addr);
                    short8 f2 = *(const short8*)(r2p + addr);
                    short8 f3 = *(const short8*)(r3p + addr);
                    acc0 = __builtin_amdgcn_mfma_f32_32x32x16_bf16(
                        wfrag[s * 2 + ch], f0, acc0, 0, 0, 0);
                    acc1 = __builtin_amdgcn_mfma_f32_32x32x16_bf16(
                        wfrag[s * 2 + ch], f1, acc1, 0, 0, 0);
                    acc0 = __builtin_amdgcn_mfma_f32_32x32x16_bf16(
                        wfrag[(3 + s) * 2 + ch], f1, acc0, 0, 0, 0);
                    acc1 = __builtin_amdgcn_mfma_f32_32x32x16_bf16(
                        wfrag[(3 + s) * 2 + ch], f2, acc1, 0, 0, 0);
                    acc0 = __builtin_amdgcn_mfma_f32_32x32x16_bf16(
                        wfrag[(6 + s) * 2 + ch], f2, acc0, 0, 0, 0);
                    acc1 = __builtin_amdgcn_mfma_f32_32x32x16_bf16(
                        wfrag[(6 + s) * 2 + ch], f3, acc1, 0, 0, 0);
                }
            }
        }

        // P4: Y stores first (ack overlaps pack/ds_write), then stage h+3,h+4
        // into slots (s0+4)%6,(s0+5)%6 — disjoint from this step's read slots;
        // prior readers of those slots were fenced by the previous barrier.
        if (wid < 7) {
            const int px0 = wid * 32;
            const int ybase0 = n * C_OUT * HW + h * WW + px0 + col;
#pragma unroll
            for (int i = 0; i < 16; ++i) {
                int ko = (i & 3) + 8 * (i >> 2) + 4 * khalf;
                Y[ybase0 + ko * HW] = acc0[i];
                Y[ybase0 + WW + ko * HW] = acc1[i];
            }
        }
        {
            char* wa = ring + ((s0 + 4) % NRING) * ROW_BYTES;
            char* wb = ring + ((s0 + 5) % NRING) * ROW_BYTES;
            if (va)      WRITE_ROW(wa, ea0, oa0, ea1, oa1);
            else if (dp) ZERO_ROW(wa);
            if (vb)      WRITE_ROW(wb, eb0, ob0, eb1, ob1);
            else if (dp) ZERO_ROW(wb);
        }
        __syncthreads();   // the ONLY barrier per 2-row step
        s0 = (s0 + 2) % NRING;
    }
#undef LOAD_ROW
#undef WRITE_ROW
#undef ZERO_ROW
}

extern "C" void kernel_launch(void* const* d_in, const int* in_sizes, int n_in,
                              void* d_out, int out_size, void* d_ws, size_t ws_size,
                              hipStream_t stream) {
    const float* X = (const float*)d_in[0];
    const float* W = (const float*)d_in[1];
    const float* B = (const float*)d_in[2];
    float* Y = (float*)d_out;
    // 256 blocks = 32 images x 8 stripes; 1 block/CU (LDS 108.5KB)
    conv3x3_rows2<<<dim3(256), dim3(NTHR), 0, stream>>>(X, W, B, Y);
}

// Round 9
// 103.122 us; speedup vs baseline: 1.0433x; 1.0208x over previous
//
#include <hip/hip_runtime.h>

typedef __attribute__((ext_vector_type(4))) float float4v;
typedef __attribute__((ext_vector_type(8))) short short8;
typedef __attribute__((ext_vector_type(16))) float f32x16;

#define C_IN 32
#define C_OUT 32
#define HH 224
#define WW 224
#define HW (HH * WW)
#define STRIPE 28                 // output rows per block; 8 stripes x 32 imgs = 256 blocks
#define RING_PX 226               // w = -1 .. 224 (halo columns at px 0 and 225)
#define PIX_STRIDE 80             // 64B data (32ch bf16) + 16B pad; conflict-free b128
#define ROW_BYTES (RING_PX * PIX_STRIDE)  // 18,080
#define NRING 6
#define NTHR 512

// fp32 -> bf16 bits, round-to-nearest-even
__device__ __forceinline__ short f2bf(float f) {
    unsigned u = __float_as_uint(f);
    u += 0x7FFFu + ((u >> 16) & 1u);
    return (short)(u >> 16);
}
__device__ __forceinline__ unsigned pack2(float e, float o) {
    return (unsigned)(unsigned short)f2bf(e) | ((unsigned)(unsigned short)f2bf(o) << 16);
}

// Volatile asm load: pins the issue point (cannot be sunk by the scheduler, which
// defeated every C-level prefetch in R4/R5/R8 — VGPR counts proved loads were
// sunk to their use). Completion is NOT tracked by the compiler: the explicit
// s_waitcnt vmcnt(0) + sched_barrier(0) below is the only fence (rule #18).
#define ALOAD(dst, addr) \
    asm volatile("global_load_dwordx4 %0, %1, off" : "=v"(dst) : "v"(addr) : "memory")

// R6/R7/R8 invariance (~8.8k cy/row regardless of barriers/occupancy/ds count)
// points at two per-row serial costs: (a) one 18-deep MFMA acc chain per row,
// (b) prefetch loads sunk to use. This version: 4 independent 9-deep chains
// (channel-split accumulators) + asm-pinned prefetch completing under the MFMA phase.
__global__ __launch_bounds__(NTHR) __attribute__((amdgpu_waves_per_eu(2, 2)))
void conv3x3_rows3(const float* __restrict__ X, const float* __restrict__ Wt,
                   const float* __restrict__ Bias, float* __restrict__ Y) {
    __shared__ __align__(16) char ring[NRING * ROW_BYTES];  // 108,480 B

    const int tid = threadIdx.x;
    const int lane = tid & 63;
    const int wid = tid >> 6;      // wave 0..7
    const int col = lane & 31;     // A: out-channel; B/C: pixel col
    const int khalf = lane >> 5;   // K-half of MFMA K=16 slice

    // --- W fragments (A operand: M=32 k_out, K=16 c-slice) ---
    short8 wfrag[18];
#pragma unroll
    for (int rs = 0; rs < 9; ++rs) {
#pragma unroll
        for (int ch = 0; ch < 2; ++ch) {
            short8 f;
#pragma unroll
            for (int j = 0; j < 8; ++j) {
                int c = ch * 16 + khalf * 8 + j;
                f[j] = f2bf(Wt[(col * C_IN + c) * 9 + rs]);  // W[k_out][c][r][s]
            }
            wfrag[rs * 2 + ch] = f;
        }
    }

    // --- Bias in C-fragment order: row(k_out) = (i&3) + 8*(i>>2) + 4*khalf ---
    f32x16 biasv;
#pragma unroll
    for (int i = 0; i < 16; ++i)
        biasv[i] = Bias[(i & 3) + 8 * (i >> 2) + 4 * khalf];
    const f32x16 zacc = {0.f};

    // --- Staging geometry: unit u = w4*16 + cp ---
    const int cp0 = tid & 15, w40 = tid >> 4;
    const int t1 = tid + NTHR;
    const bool has1 = (tid < 896 - NTHR);
    const int cp1 = t1 & 15, w41 = t1 >> 4;
    const int ge0 = (2 * cp0) * HW + 4 * w40;
    const int go0 = ge0 + HW;
    const int ge1 = (2 * cp1) * HW + 4 * w41;
    const int go1 = ge1 + HW;

    const int bid = blockIdx.x;
    const int n = bid >> 3;
    const int h1 = (bid & 7) * STRIPE;
    const float* Xn = X + n * C_IN * HW;

    float4v ea0, oa0, ea1, oa1;   // staged row h+3
    float4v eb0, ob0, eb1, ob1;   // staged row h+4
    const short8 z8 = {0, 0, 0, 0, 0, 0, 0, 0};

#define WRITE_ROW(sb, E0, O0, E1, O1) do {                         \
        char* wb0 = (sb) + (1 + 4 * w40) * PIX_STRIDE + cp0 * 4;   \
        *(unsigned*)(wb0                  ) = pack2(E0[0], O0[0]); \
        *(unsigned*)(wb0 +     PIX_STRIDE ) = pack2(E0[1], O0[1]); \
        *(unsigned*)(wb0 + 2 * PIX_STRIDE ) = pack2(E0[2], O0[2]); \
        *(unsigned*)(wb0 + 3 * PIX_STRIDE ) = pack2(E0[3], O0[3]); \
        if (has1) {                                                \
            char* wb1 = (sb) + (1 + 4 * w41) * PIX_STRIDE + cp1 * 4; \
            *(unsigned*)(wb1                  ) = pack2(E1[0], O1[0]); \
            *(unsigned*)(wb1 +     PIX_STRIDE ) = pack2(E1[1], O1[1]); \
            *(unsigned*)(wb1 + 2 * PIX_STRIDE ) = pack2(E1[2], O1[2]); \
            *(unsigned*)(wb1 + 3 * PIX_STRIDE ) = pack2(E1[3], O1[3]); \
        }                                                          \
        if (tid < 8) {                                             \
            int px = (tid < 4) ? 0 : (RING_PX - 1);                \
            *(short8*)((sb) + px * PIX_STRIDE + (tid & 3) * 16) = z8; \
        }                                                          \
    } while (0)

#define ZERO_ROW(sb) do {                                          \
        for (int i = tid; i < ROW_BYTES / 16; i += NTHR)           \
            *(short8*)((sb) + i * 16) = z8;                        \
    } while (0)

    // ===== Prologue: rows h1-1 .. h1+2 into slots (row+6)%6 (plain loads) =====
#pragma unroll
    for (int j = 0; j < 4; ++j) {
        int hh = h1 - 1 + j;
        char* sb = ring + ((hh + NRING) % NRING) * ROW_BYTES;
        if (hh >= 0) {
            const float* rp = Xn + hh * WW;
            ea0 = *(const float4v*)(rp + ge0);
            oa0 = *(const float4v*)(rp + go0);
            if (has1) {
                ea1 = *(const float4v*)(rp + ge1);
                oa1 = *(const float4v*)(rp + go1);
            }
            WRITE_ROW(sb, ea0, oa0, ea1, oa1);
        } else {
            ZERO_ROW(sb);
        }
    }
    __syncthreads();

    // ===== Main loop: compute rows (h, h+1); prefetch rows (h+3, h+4) =====
    int s0 = (h1 + 5) % NRING;            // slot of row h-1
    const int pcol = col * PIX_STRIDE + khalf * 16;

    for (int h = h1; h < h1 + STRIPE; h += 2) {
        const int ha = h + 3, hb = h + 4;
        const bool dp = (hb <= h1 + STRIPE);       // block-uniform
        const bool va = dp && (ha < HH);
        const bool vb = dp && (hb < HH);

        // P1: asm-pinned prefetch issue (completion fenced before P4 pack)
        if (va) {
            const float* rp = Xn + ha * WW;
            ALOAD(ea0, rp + ge0);
            ALOAD(oa0, rp + go0);
            if (has1) {
                ALOAD(ea1, rp + ge1);
                ALOAD(oa1, rp + go1);
            }
        }
        if (vb) {
            const float* rp = Xn + hb * WW;
            ALOAD(eb0, rp + ge0);
            ALOAD(ob0, rp + go0);
            if (has1) {
                ALOAD(eb1, rp + ge1);
                ALOAD(ob1, rp + go1);
            }
        }

        // P2: compute rows h,h+1 — FOUR independent 9-deep MFMA chains
        // (acc{row}{ch-half}); a-chain carries bias, b-chain starts at 0.
        const char* r0p = ring + s0 * ROW_BYTES;
        const char* r1p = ring + ((s0 + 1) % NRING) * ROW_BYTES;
        const char* r2p = ring + ((s0 + 2) % NRING) * ROW_BYTES;
        const char* r3p = ring + ((s0 + 3) % NRING) * ROW_BYTES;
        f32x16 acc0a, acc0b, acc1a, acc1b;
        if (wid < 7) {
            const int px0 = wid * 32;
            acc0a = biasv; acc0b = zacc;
            acc1a = biasv; acc1b = zacc;
            const int pb = px0 * PIX_STRIDE + pcol;
#pragma unroll
            for (int s = 0; s < 3; ++s) {
#pragma unroll
                for (int ch = 0; ch < 2; ++ch) {
                    const int addr = pb + s * PIX_STRIDE + ch * 32;
                    short8 f0 = *(const short8*)(r0p + addr);
                    short8 f1 = *(const short8*)(r1p + addr);
                    short8 f2 = *(const short8*)(r2p + addr);
                    short8 f3 = *(const short8*)(r3p + addr);
                    f32x16& a0 = ch ? acc0b : acc0a;
                    f32x16& a1 = ch ? acc1b : acc1a;
                    a0 = __builtin_amdgcn_mfma_f32_32x32x16_bf16(
                        wfrag[s * 2 + ch], f0, a0, 0, 0, 0);
                    a1 = __builtin_amdgcn_mfma_f32_32x32x16_bf16(
                        wfrag[s * 2 + ch], f1, a1, 0, 0, 0);
                    a0 = __builtin_amdgcn_mfma_f32_32x32x16_bf16(
                        wfrag[(3 + s) * 2 + ch], f1, a0, 0, 0, 0);
                    a1 = __builtin_amdgcn_mfma_f32_32x32x16_bf16(
                        wfrag[(3 + s) * 2 + ch], f2, a1, 0, 0, 0);
                    a0 = __builtin_amdgcn_mfma_f32_32x32x16_bf16(
                        wfrag[(6 + s) * 2 + ch], f2, a0, 0, 0, 0);
                    a1 = __builtin_amdgcn_mfma_f32_32x32x16_bf16(
                        wfrag[(6 + s) * 2 + ch], f3, a1, 0, 0, 0);
                }
            }
        }

        // Fence: prefetch loads complete (they had the whole MFMA phase).
        // sched_barrier stops register-only pack ops hoisting above the wait (rule #18).
        if (dp) {
            asm volatile("s_waitcnt vmcnt(0)" ::: "memory");
            __builtin_amdgcn_sched_barrier(0);
        }

        // P3: Y stores (issued now; they drain at the barrier, overlapped by P4)
        if (wid < 7) {
            const int px0 = wid * 32;
            f32x16 acc0, acc1;
#pragma unroll
            for (int i = 0; i < 16; ++i) {
                acc0[i] = acc0a[i] + acc0b[i];
                acc1[i] = acc1a[i] + acc1b[i];
            }
            const int ybase0 = n * C_OUT * HW + h * WW + px0 + col;
#pragma unroll
            for (int i = 0; i < 16; ++i) {
                int ko = (i & 3) + 8 * (i >> 2) + 4 * khalf;
                Y[ybase0 + ko * HW] = acc0[i];
                Y[ybase0 + WW + ko * HW] = acc1[i];
            }
        }

        // P4: pack + ds_write rows h+3,h+4 into disjoint slots
        {
            char* wa = ring + ((s0 + 4) % NRING) * ROW_BYTES;
            char* wb = ring + ((s0 + 5) % NRING) * ROW_BYTES;
            if (va)      WRITE_ROW(wa, ea0, oa0, ea1, oa1);
            else if (dp) ZERO_ROW(wa);
            if (vb)      WRITE_ROW(wb, eb0, ob0, eb1, ob1);
            else if (dp) ZERO_ROW(wb);
        }
        __syncthreads();   // one barrier per 2-row step
        s0 = (s0 + 2) % NRING;
    }
#undef WRITE_ROW
#undef ZERO_ROW
}

extern "C" void kernel_launch(void* const* d_in, const int* in_sizes, int n_in,
                              void* d_out, int out_size, void* d_ws, size_t ws_size,
                              hipStream_t stream) {
    const float* X = (const float*)d_in[0];
    const float* W = (const float*)d_in[1];
    const float* B = (const float*)d_in[2];
    float* Y = (float*)d_out;
    // 256 blocks = 32 images x 8 stripes; 1 block/CU (LDS 108.5KB)
    conv3x3_rows3<<<dim3(256), dim3(NTHR), 0, stream>>>(X, W, B, Y);
}